// Round 4
// baseline (506.803 us; speedup 1.0000x reference)
//
#include <hip/hip_runtime.h>

// FGPM geometry features: 6 points (x,y) per row -> 15 dists, 20 angles(deg), 20 areas.
// Output layout: out[b*55 + f], f = [dist(15) | angle(20) | area(20)] in
// lexicographic pair/triplet order (i<j<k over 6 keys).
//
// Memory-bound: 96 MB in + 440 MB out -> ~85 us floor at 6.3 TB/s.
// R2: float4 LDS-transpose writeback (-40 us). R3: cheap math (rsq, poly acos,
// shared pair diffs) -> ZERO effect => kernel phase (~220 us) is not VALU- or
// issue-bound. Remaining untested variable (constant across all prior
// versions): nontemporal output stores. The harness fill kernel sustains
// 6.35 TB/s with PLAIN stores; our nt stream runs ~2.4 TB/s effective.
// Hypothesis: nt bypasses the L2 write-absorb path with limited outstanding
// write capacity. Inputs are read-once (no reuse to protect), so nt buys
// nothing. This version: plain stores, everything else identical to R3.

constexpr int T  = 64;    // threads per block; 2,000,000 % 64 == 0
constexpr int NF = 55;    // features per row

typedef float vfloat4 __attribute__((ext_vector_type(4)));

// pair index for i<j over 6 keys, lexicographic
__host__ __device__ constexpr int PIDX(int i, int j) {
    return 5 * i - (i * (i - 1)) / 2 + (j - i - 1);
}

__device__ __forceinline__ float acos_deg(float x) {
    // x in [-1,1]. Hastings 8-term: acos(ax) = sqrt(1-ax)*P(ax), ax=|x|.
    float ax = fabsf(x);
    float s  = __builtin_amdgcn_sqrtf(1.0f - ax);
    float p  = -0.0012624911f;
    p = fmaf(p, ax,  0.0066700901f);
    p = fmaf(p, ax, -0.0170881256f);
    p = fmaf(p, ax,  0.0308918810f);
    p = fmaf(p, ax, -0.0501743046f);
    p = fmaf(p, ax,  0.0889789874f);
    p = fmaf(p, ax, -0.2145988016f);
    p = fmaf(p, ax,  1.5707963050f);
    float r = s * p * 57.29577951308232f;   // degrees for x >= 0
    return x < 0.0f ? 180.0f - r : r;
}

__global__ __launch_bounds__(T) void fgpm_kernel(
    const float2* __restrict__ p0, const float2* __restrict__ p1,
    const float2* __restrict__ p2, const float2* __restrict__ p3,
    const float2* __restrict__ p4, const float2* __restrict__ p5,
    float* __restrict__ out, int B)
{
    __shared__ __align__(16) float lds[T * NF];
    const int tid = threadIdx.x;
    const long b  = (long)blockIdx.x * T + tid;

    float2 pt[6];
    if (b < (long)B) {
        pt[0] = p0[b]; pt[1] = p1[b]; pt[2] = p2[b];
        pt[3] = p3[b]; pt[4] = p4[b]; pt[5] = p5[b];
    } else {
        #pragma unroll
        for (int i = 0; i < 6; ++i) pt[i] = make_float2(0.f, 0.f);
    }

    float* row = &lds[tid * NF];

    // ---- 15 pair diffs, squared norms, distances ----
    float dx[15], dy[15], nn[15];
    #pragma unroll
    for (int i = 0; i < 6; ++i) {
        #pragma unroll
        for (int j = i + 1; j < 6; ++j) {
            const int q = PIDX(i, j);
            dx[q] = pt[i].x - pt[j].x;
            dy[q] = pt[i].y - pt[j].y;
            nn[q] = fmaf(dx[q], dx[q], dy[q] * dy[q]);
            row[q] = __builtin_amdgcn_sqrtf(nn[q]);
        }
    }

    // ---- 20 triplet angles (at middle vertex j) + 20 areas ----
    // v1 = P1-P2 = d(i,j);  v2 = P3-P2 = -d(j,k)
    {
        int t = 0;
        #pragma unroll
        for (int i = 0; i < 6; ++i) {
            #pragma unroll
            for (int j = i + 1; j < 6; ++j) {
                const int q1 = PIDX(i, j);
                #pragma unroll
                for (int k = j + 1; k < 6; ++k) {
                    const int q2 = PIDX(j, k);
                    float dot = -fmaf(dx[q1], dx[q2], dy[q1] * dy[q2]);
                    float c   = dot * __builtin_amdgcn_rsqf(nn[q1] * nn[q2]);
                    c = fminf(1.0f, fmaxf(-1.0f, c));
                    row[15 + t] = acos_deg(c);
                    float cross = fmaf(dx[q1], dy[q2], -(dy[q1] * dx[q2]));
                    row[35 + t] = 0.5f * fabsf(cross);
                    ++t;
                }
            }
        }
    }

    __syncthreads();

    // ---- coalesced float4 transpose writeback (plain stores) ----
    const long blk_start = (long)blockIdx.x * T;   // first row of this block
    float* o = out + blk_start * NF;

    if (blk_start + T <= (long)B) {
        // Full block: T*NF floats = 880 float4s, flat on both sides.
        const vfloat4* l4 = reinterpret_cast<const vfloat4*>(lds);
        vfloat4*       o4 = reinterpret_cast<vfloat4*>(o);
        constexpr int N4    = T * NF / 4;     // 880
        constexpr int FULLK = N4 / T;         // 13
        constexpr int RES   = N4 - FULLK * T; // 48
        #pragma unroll
        for (int k = 0; k < FULLK; ++k)
            o4[tid + k * T] = l4[tid + k * T];
        if (tid < RES)
            o4[tid + FULLK * T] = l4[tid + FULLK * T];
    } else {
        // Partial tail block (not hit for B % T == 0): scalar fallback.
        const int nrows = (int)((long)B - blk_start);
        const int total = nrows * NF;
        for (int g = tid; g < total; g += T)
            o[g] = lds[g];
    }
}

extern "C" void kernel_launch(void* const* d_in, const int* in_sizes, int n_in,
                              void* d_out, int out_size, void* d_ws, size_t ws_size,
                              hipStream_t stream) {
    const int B = in_sizes[0] / 2;   // inputs are (B, 2) float32
    const int grid = (B + T - 1) / T;
    fgpm_kernel<<<grid, dim3(T), 0, stream>>>(
        (const float2*)d_in[0], (const float2*)d_in[1], (const float2*)d_in[2],
        (const float2*)d_in[3], (const float2*)d_in[4], (const float2*)d_in[5],
        (float*)d_out, B);
}